// Round 1
// baseline (531.482 us; speedup 1.0000x reference)
//
#include <hip/hip_runtime.h>
#include <hip/hip_bf16.h>
#include <cstdint>
#include <cstddef>

#define NS_ROWS 4096
#define NT_ROWS 4096
#define DIM 1024
#define NC 4

typedef __attribute__((ext_vector_type(8))) short bf16x8;
typedef __attribute__((ext_vector_type(4))) float f32x4;

#define GLOBAL_AS __attribute__((address_space(1)))
#define LDS_AS __attribute__((address_space(3)))

// ---------------- ws accumulator layout (floats) ----------------
// [0] sum_cls   [1] sum_ent
// [2..5] n_s[c] [6..9] n_t[c] [10..13] tr_t[c]
// [14..17] ss_s [18..21] ss_t [22..25] ss_st
#define ACC_N 26

__device__ __forceinline__ float bf16_round(float x, unsigned short* bits) {
    uint32_t u = __float_as_uint(x);
    uint32_t b = (u + 0x7FFFu + ((u >> 16) & 1u)) >> 16;   // RNE
    *bits = (unsigned short)b;
    return __uint_as_float(b << 16);
}

// Convert features to bf16 and compute per-row squared norms of the ROUNDED rows.
// grid = NS+NT blocks of 128 threads; one block per row (128*8 = 1024 cols).
__global__ void prep_feat(const float* __restrict__ FS, const float* __restrict__ FT,
                          unsigned short* __restrict__ fs, unsigned short* __restrict__ ft,
                          float* __restrict__ ns, float* __restrict__ nt) {
    int b = blockIdx.x;
    const float* src;
    unsigned short* dst;
    float* nrm;
    if (b < NS_ROWS) { src = FS + (size_t)b * DIM; dst = fs + (size_t)b * DIM; nrm = ns + b; }
    else { int r = b - NS_ROWS; src = FT + (size_t)r * DIM; dst = ft + (size_t)r * DIM; nrm = nt + r; }
    int t = threadIdx.x;
    float4 v0 = ((const float4*)src)[t * 2];
    float4 v1 = ((const float4*)src)[t * 2 + 1];
    float vals[8] = {v0.x, v0.y, v0.z, v0.w, v1.x, v1.y, v1.z, v1.w};
    unsigned short us[8];
    float ssum = 0.f;
#pragma unroll
    for (int i = 0; i < 8; ++i) {
        float f = bf16_round(vals[i], &us[i]);
        ssum += f * f;
    }
    bf16x8 pack;
#pragma unroll
    for (int i = 0; i < 8; ++i) pack[i] = (short)us[i];
    *(bf16x8*)(dst + (size_t)t * 8) = pack;

    for (int off = 32; off; off >>= 1) ssum += __shfl_xor(ssum, off);
    __shared__ float partial[2];
    if ((t & 63) == 0) partial[t >> 6] = ssum;
    __syncthreads();
    if (t == 0) *nrm = partial[0] + partial[1];
}

// Per-row work on logits: CE(source), entropy/pseudo/w (target).
// grid = 32 blocks x 256 threads (8192 rows total).
__global__ void prep_rows(const float* __restrict__ LS, const int* __restrict__ labels,
                          const float* __restrict__ LT, int* __restrict__ clsT,
                          float* __restrict__ wt2, float* __restrict__ acc) {
    __shared__ float sacc[ACC_N];
    int t = threadIdx.x;
    if (t < ACC_N) sacc[t] = 0.f;
    __syncthreads();
    int gid = blockIdx.x * 256 + t;
    const float EPSF = 1e-8f;
    if (gid < NS_ROWS) {
        float4 l = ((const float4*)LS)[gid];
        float m = fmaxf(fmaxf(l.x, l.y), fmaxf(l.z, l.w));
        float e = expf(l.x - m) + expf(l.y - m) + expf(l.z - m) + expf(l.w - m);
        float lse = m + logf(e);
        int lab = labels[gid];
        float ll = (lab == 0) ? l.x : (lab == 1) ? l.y : (lab == 2) ? l.z : l.w;
        atomicAdd(&sacc[0], lse - ll);
        atomicAdd(&sacc[2 + lab], 1.0f);
    } else {
        int j = gid - NS_ROWS;
        float4 l = ((const float4*)LT)[j];
        float m = fmaxf(fmaxf(l.x, l.y), fmaxf(l.z, l.w));
        float p0 = expf(l.x - m), p1 = expf(l.y - m), p2 = expf(l.z - m), p3 = expf(l.w - m);
        float s = p0 + p1 + p2 + p3;
        p0 /= s; p1 /= s; p2 /= s; p3 /= s;
        float ent = p0 * logf(p0 + EPSF) + p1 * logf(p1 + EPSF) +
                    p2 * logf(p2 + EPSF) + p3 * logf(p3 + EPSF);
        int am = 0; float bm = p0;
        if (p1 > bm) { bm = p1; am = 1; }
        if (p2 > bm) { bm = p2; am = 2; }
        if (p3 > bm) { bm = p3; am = 3; }
        float sumsq = p0 * p0 + p1 * p1 + p2 * p2 + p3 * p3;
        const float INV_LOG2 = 1.44269504088896340736f;
        float h2 = -logf(sumsq + EPSF) * INV_LOG2;
        float w = 1.0f - h2 / (2.0f + EPSF);
        float w2 = w * w;
        clsT[j] = am;
        wt2[j] = w2;
        atomicAdd(&sacc[1], ent);
        atomicAdd(&sacc[6 + am], 1.0f);
        atomicAdd(&sacc[10 + am], w2);
    }
    __syncthreads();
    if (t < ACC_N && sacc[t] != 0.f) atomicAdd(&acc[t], sacc[t]);
}

// Fused GEMM (A@B^T) + RBF + masked per-class reduction of K^2.
// 128x128 tile, 4 waves (2x2 of 64x64), BK=32, mfma 16x16x32 bf16.
// symmetric=1: grid enumerates upper-triangular tile pairs; off-diag scaled x2.
__global__ __launch_bounds__(256)
void gemm_reduce(const unsigned short* __restrict__ A, const unsigned short* __restrict__ B,
                 const float* __restrict__ nA, const float* __restrict__ nB,
                 const int* __restrict__ cA, const int* __restrict__ cB,
                 const float* __restrict__ wA, const float* __restrict__ wB,
                 float* __restrict__ out, int symmetric) {
    __shared__ unsigned short As[128 * 32];
    __shared__ unsigned short Bs[128 * 32];

    int bid = blockIdx.x;
    int ti, tj;
    if (symmetric) {
        int r = (int)((sqrtf(8.0f * (float)bid + 1.0f) - 1.0f) * 0.5f);
        while ((r + 1) * (r + 2) / 2 <= bid) ++r;
        while (r * (r + 1) / 2 > bid) --r;
        int c = bid - r * (r + 1) / 2;
        ti = c; tj = r;                 // ti <= tj
    } else {
        ti = bid >> 5;                  // NT/128 = 32 col-tiles
        tj = bid & 31;
    }

    int tid = threadIdx.x;
    int lane = tid & 63;
    int wid = tid >> 6;
    int wr = wid >> 1, wc = wid & 1;

    const unsigned short* Ab = A + (size_t)(ti * 128) * DIM;
    const unsigned short* Bb = B + (size_t)(tj * 128) * DIM;

    int srow = tid >> 2;                // 0..63
    int scol = (tid & 3) * 8;           // 0,8,16,24

    f32x4 acc[4][4];
#pragma unroll
    for (int m = 0; m < 4; ++m)
#pragma unroll
        for (int n = 0; n < 4; ++n) acc[m][n] = (f32x4)(0.f);

    int lr = lane & 15;
    int lk = (lane >> 4) * 8;

    for (int kt = 0; kt < DIM / 32; ++kt) {
        int k0 = kt * 32;
        __syncthreads();
        __builtin_amdgcn_global_load_lds(
            (const GLOBAL_AS void*)(Ab + (size_t)srow * DIM + k0 + scol),
            (LDS_AS void*)(As + tid * 8), 16, 0, 0);
        __builtin_amdgcn_global_load_lds(
            (const GLOBAL_AS void*)(Ab + (size_t)(srow + 64) * DIM + k0 + scol),
            (LDS_AS void*)(As + 2048 + tid * 8), 16, 0, 0);
        __builtin_amdgcn_global_load_lds(
            (const GLOBAL_AS void*)(Bb + (size_t)srow * DIM + k0 + scol),
            (LDS_AS void*)(Bs + tid * 8), 16, 0, 0);
        __builtin_amdgcn_global_load_lds(
            (const GLOBAL_AS void*)(Bb + (size_t)(srow + 64) * DIM + k0 + scol),
            (LDS_AS void*)(Bs + 2048 + tid * 8), 16, 0, 0);
        __syncthreads();

        bf16x8 af[4], bfr[4];
#pragma unroll
        for (int f = 0; f < 4; ++f)
            af[f] = *(const bf16x8*)(As + (wr * 64 + f * 16 + lr) * 32 + lk);
#pragma unroll
        for (int f = 0; f < 4; ++f)
            bfr[f] = *(const bf16x8*)(Bs + (wc * 64 + f * 16 + lr) * 32 + lk);
#pragma unroll
        for (int m = 0; m < 4; ++m)
#pragma unroll
            for (int n = 0; n < 4; ++n)
                acc[m][n] = __builtin_amdgcn_mfma_f32_16x16x32_bf16(af[m], bfr[n], acc[m][n], 0, 0, 0);
    }

    // ---- fused epilogue: d2 -> K^2 -> masked per-class accumulate ----
    float factor = (symmetric && (ti != tj)) ? 2.0f : 1.0f;
    int rowBase = ti * 128 + wr * 64;
    int colBase = tj * 128 + wc * 64;

    float cn[4], cw[4];
    int cc[4];
#pragma unroll
    for (int f = 0; f < 4; ++f) {
        int gj = colBase + f * 16 + lr;
        cn[f] = nB[gj];
        cw[f] = wB ? wB[gj] : 1.0f;
        cc[f] = cB[gj];
    }

    const float NEGF = (-2.0f / (2.0f * 32.0f * 32.0f + 1e-8f)) * 1.44269504088896340736f;
    float lacc[NC] = {0.f, 0.f, 0.f, 0.f};

#pragma unroll
    for (int m = 0; m < 4; ++m) {
#pragma unroll
        for (int j = 0; j < 4; ++j) {
            int gi = rowBase + m * 16 + (lane >> 4) * 4 + j;
            float rn = nA[gi];
            float rw = wA ? wA[gi] : 1.0f;
            int rc = cA[gi];
#pragma unroll
            for (int n = 0; n < 4; ++n) {
                float dot = acc[m][n][j];
                float d2 = rn + cn[n] - 2.0f * dot;
                d2 = fmaxf(d2, 0.0f);
                float k2 = exp2f(d2 * NEGF);        // = K^2
                float v = k2 * rw * cw[n];
#pragma unroll
                for (int c = 0; c < NC; ++c)
                    lacc[c] += ((rc == c) && (cc[n] == c)) ? v : 0.0f;
            }
        }
    }

#pragma unroll
    for (int c = 0; c < NC; ++c) {
        float v = lacc[c];
        for (int off = 32; off; off >>= 1) v += __shfl_xor(v, off);
        if (lane == 0) atomicAdd(&out[c], factor * v);
    }
}

__global__ void finalize_kernel(const float* __restrict__ acc, float* __restrict__ out) {
    if (threadIdx.x != 0 || blockIdx.x != 0) return;
    const double EPS = 1e-8;
    const double LOG2 = 0.6931471805599453;
    double loss_cls = (double)acc[0] / NS_ROWS;
    double loss_ent = -(double)acc[1] / NT_ROWS;
    double creda_sum = 0.0, n_valid = 0.0;
    for (int c = 0; c < NC; ++c) {
        double nsc = acc[2 + c], ntc = acc[6 + c], trt = acc[10 + c];
        double sss = acc[14 + c], sst = acc[18 + c], ssst = acc[22 + c];
        double trs = nsc;
        double info_s = sss / ((trs + EPS) * (trs + EPS));
        double h_s = -log(info_s + EPS) / LOG2;
        double info_t = sst / ((trt + EPS) * (trt + EPS));
        double h_t = -log(info_t + EPS) / LOG2;
        double trm = trs + trt;
        double ssm = sss + 2.0 * ssst + sst;
        double info_m = ssm / ((trm + EPS) * (trm + EPS));
        double h_m = -log(info_m + EPS) / LOG2;
        double pc = h_m - 0.5 * (h_s + h_t);
        if (nsc >= 2.0 && ntc >= 2.0) { creda_sum += pc; n_valid += 1.0; }
    }
    double creda = (n_valid > 0.0) ? creda_sum / n_valid : 0.0;
    out[0] = (float)(loss_cls + 1.0 * creda + 0.1 * loss_ent);
}

extern "C" void kernel_launch(void* const* d_in, const int* in_sizes, int n_in,
                              void* d_out, int out_size, void* d_ws, size_t ws_size,
                              hipStream_t stream) {
    const float* FS = (const float*)d_in[0];
    const float* LS = (const float*)d_in[1];
    const float* FT = (const float*)d_in[2];
    const float* LT = (const float*)d_in[3];
    const int* LAB = (const int*)d_in[4];

    char* ws = (char*)d_ws;
    unsigned short* fs = (unsigned short*)(ws);                       // 8 MB
    unsigned short* ft = (unsigned short*)(ws + 8388608);             // 8 MB
    float* ns_ = (float*)(ws + 16777216);                             // 16 KB
    float* nt_ = ns_ + NS_ROWS;                                       // 16 KB
    float* wt2 = nt_ + NT_ROWS;                                       // 16 KB
    int* clsT = (int*)(wt2 + NT_ROWS);                                // 16 KB
    float* acc = (float*)(clsT + NT_ROWS);                            // 26 floats

    hipMemsetAsync(acc, 0, ACC_N * sizeof(float), stream);

    prep_feat<<<NS_ROWS + NT_ROWS, 128, 0, stream>>>(FS, FT, fs, ft, ns_, nt_);
    prep_rows<<<32, 256, 0, stream>>>(LS, LAB, LT, clsT, wt2, acc);

    // ss_s: symmetric source-source, 33*32/2 + 32 = 528 tiles
    gemm_reduce<<<528, 256, 0, stream>>>(fs, fs, ns_, ns_, LAB, LAB,
                                         nullptr, nullptr, acc + 14, 1);
    // ss_t: symmetric target-target with w^2 weights
    gemm_reduce<<<528, 256, 0, stream>>>(ft, ft, nt_, nt_, clsT, clsT,
                                         wt2, wt2, acc + 18, 1);
    // ss_st: source-target, full grid
    gemm_reduce<<<1024, 256, 0, stream>>>(fs, ft, ns_, nt_, LAB, clsT,
                                          nullptr, nullptr, acc + 22, 0);

    finalize_kernel<<<1, 1, 0, stream>>>(acc, (float*)d_out);
}

// Round 2
// 156.682 us; speedup vs baseline: 3.3921x; 3.3921x over previous
//
#include <hip/hip_runtime.h>
#include <hip/hip_bf16.h>
#include <cstdint>
#include <cstddef>

#define NS_ROWS 4096
#define NT_ROWS 4096
#define DIM 1024
#define NC 4

typedef __attribute__((ext_vector_type(8))) short bf16x8;
typedef __attribute__((ext_vector_type(4))) float f32x4;

#define GLOBAL_AS __attribute__((address_space(1)))
#define LDS_AS __attribute__((address_space(3)))

// ---------------- ws accumulator layout (floats) ----------------
// [0] sum_cls   [1] sum_ent
// [2..5] n_s[c] [6..9] n_t[c] [10..13] tr_t[c]
// [14..17] ss_s [18..21] ss_t [22..25] ss_st
#define ACC_N 26

__device__ __forceinline__ float bf16_round(float x, unsigned short* bits) {
    uint32_t u = __float_as_uint(x);
    uint32_t b = (u + 0x7FFFu + ((u >> 16) & 1u)) >> 16;   // RNE
    *bits = (unsigned short)b;
    return __uint_as_float(b << 16);
}

// Convert features to bf16 and compute per-row squared norms of the ROUNDED rows.
// grid = NS+NT blocks of 128 threads; one block per row (128*8 = 1024 cols).
__global__ void prep_feat(const float* __restrict__ FS, const float* __restrict__ FT,
                          unsigned short* __restrict__ fs, unsigned short* __restrict__ ft,
                          float* __restrict__ ns, float* __restrict__ nt) {
    int b = blockIdx.x;
    const float* src;
    unsigned short* dst;
    float* nrm;
    if (b < NS_ROWS) { src = FS + (size_t)b * DIM; dst = fs + (size_t)b * DIM; nrm = ns + b; }
    else { int r = b - NS_ROWS; src = FT + (size_t)r * DIM; dst = ft + (size_t)r * DIM; nrm = nt + r; }
    int t = threadIdx.x;
    float4 v0 = ((const float4*)src)[t * 2];
    float4 v1 = ((const float4*)src)[t * 2 + 1];
    float vals[8] = {v0.x, v0.y, v0.z, v0.w, v1.x, v1.y, v1.z, v1.w};
    unsigned short us[8];
    float ssum = 0.f;
#pragma unroll
    for (int i = 0; i < 8; ++i) {
        float f = bf16_round(vals[i], &us[i]);
        ssum += f * f;
    }
    bf16x8 pack;
#pragma unroll
    for (int i = 0; i < 8; ++i) pack[i] = (short)us[i];
    *(bf16x8*)(dst + (size_t)t * 8) = pack;

    for (int off = 32; off; off >>= 1) ssum += __shfl_xor(ssum, off);
    __shared__ float partial[2];
    if ((t & 63) == 0) partial[t >> 6] = ssum;
    __syncthreads();
    if (t == 0) *nrm = partial[0] + partial[1];
}

// Per-row work on logits: CE(source), entropy/pseudo/w (target).
// grid = 32 blocks x 256 threads (8192 rows total).
__global__ void prep_rows(const float* __restrict__ LS, const int* __restrict__ labels,
                          const float* __restrict__ LT, int* __restrict__ clsT,
                          float* __restrict__ wt2, float* __restrict__ acc) {
    __shared__ float sacc[ACC_N];
    int t = threadIdx.x;
    if (t < ACC_N) sacc[t] = 0.f;
    __syncthreads();
    int gid = blockIdx.x * 256 + t;
    const float EPSF = 1e-8f;
    if (gid < NS_ROWS) {
        float4 l = ((const float4*)LS)[gid];
        float m = fmaxf(fmaxf(l.x, l.y), fmaxf(l.z, l.w));
        float e = expf(l.x - m) + expf(l.y - m) + expf(l.z - m) + expf(l.w - m);
        float lse = m + logf(e);
        int lab = labels[gid];
        float ll = (lab == 0) ? l.x : (lab == 1) ? l.y : (lab == 2) ? l.z : l.w;
        atomicAdd(&sacc[0], lse - ll);
        atomicAdd(&sacc[2 + lab], 1.0f);
    } else {
        int j = gid - NS_ROWS;
        float4 l = ((const float4*)LT)[j];
        float m = fmaxf(fmaxf(l.x, l.y), fmaxf(l.z, l.w));
        float p0 = expf(l.x - m), p1 = expf(l.y - m), p2 = expf(l.z - m), p3 = expf(l.w - m);
        float s = p0 + p1 + p2 + p3;
        p0 /= s; p1 /= s; p2 /= s; p3 /= s;
        float ent = p0 * logf(p0 + EPSF) + p1 * logf(p1 + EPSF) +
                    p2 * logf(p2 + EPSF) + p3 * logf(p3 + EPSF);
        int am = 0; float bm = p0;
        if (p1 > bm) { bm = p1; am = 1; }
        if (p2 > bm) { bm = p2; am = 2; }
        if (p3 > bm) { bm = p3; am = 3; }
        float sumsq = p0 * p0 + p1 * p1 + p2 * p2 + p3 * p3;
        const float INV_LOG2 = 1.44269504088896340736f;
        float h2 = -logf(sumsq + EPSF) * INV_LOG2;
        float w = 1.0f - h2 / (2.0f + EPSF);
        float w2 = w * w;
        clsT[j] = am;
        wt2[j] = w2;
        atomicAdd(&sacc[1], ent);
        atomicAdd(&sacc[6 + am], 1.0f);
        atomicAdd(&sacc[10 + am], w2);
    }
    __syncthreads();
    if (t < ACC_N && sacc[t] != 0.f) atomicAdd(&acc[t], sacc[t]);
}

// Fused GEMM (A@B^T) + RBF + masked per-class reduction of K^2.
// 128x128 tile, 4 waves (2x2 of 64x64), BK=32, mfma 16x16x32 bf16.
// 2-phase double-buffered pipeline (T3 minimum recipe): STAGE(next) issued
// BEFORE ds_read+MFMA of current; single barrier per K-step drains it.
// symmetric=1: grid enumerates upper-triangular tile pairs; off-diag scaled x2.
__global__ __launch_bounds__(256, 4)
void gemm_reduce(const unsigned short* __restrict__ A, const unsigned short* __restrict__ B,
                 const float* __restrict__ nA, const float* __restrict__ nB,
                 const int* __restrict__ cA, const int* __restrict__ cB,
                 const float* __restrict__ wA, const float* __restrict__ wB,
                 float* __restrict__ out, int symmetric) {
    __shared__ unsigned short As[2][128 * 32];
    __shared__ unsigned short Bs[2][128 * 32];
    __shared__ float sred[NC];

    int bid = blockIdx.x;
    int ti, tj;
    if (symmetric) {
        int r = (int)((sqrtf(8.0f * (float)bid + 1.0f) - 1.0f) * 0.5f);
        while ((r + 1) * (r + 2) / 2 <= bid) ++r;
        while (r * (r + 1) / 2 > bid) --r;
        int c = bid - r * (r + 1) / 2;
        ti = c; tj = r;                 // ti <= tj
    } else {
        ti = bid >> 5;                  // 32 col-tiles
        tj = bid & 31;
    }

    int tid = threadIdx.x;
    int lane = tid & 63;
    int wid = tid >> 6;
    int wr = wid >> 1, wc = wid & 1;

    const unsigned short* Ab = A + (size_t)(ti * 128) * DIM;
    const unsigned short* Bb = B + (size_t)(tj * 128) * DIM;

    int srow = tid >> 2;                // 0..63
    int scol = (tid & 3) * 8;           // 0,8,16,24 (shorts)

    f32x4 acc[4][4];
#pragma unroll
    for (int m = 0; m < 4; ++m)
#pragma unroll
        for (int n = 0; n < 4; ++n) acc[m][n] = (f32x4)(0.f);

    int lr = lane & 15;
    int lk = (lane >> 4) * 8;

    // ---- staging helper: 4 x global_load_lds (16B each) per thread ----
#define STAGE(buf, kt)                                                            \
    do {                                                                          \
        int k0_ = (kt) * 32;                                                      \
        __builtin_amdgcn_global_load_lds(                                         \
            (const GLOBAL_AS void*)(Ab + (size_t)srow * DIM + k0_ + scol),        \
            (LDS_AS void*)(As[buf] + tid * 8), 16, 0, 0);                         \
        __builtin_amdgcn_global_load_lds(                                         \
            (const GLOBAL_AS void*)(Ab + (size_t)(srow + 64) * DIM + k0_ + scol), \
            (LDS_AS void*)(As[buf] + 2048 + tid * 8), 16, 0, 0);                  \
        __builtin_amdgcn_global_load_lds(                                         \
            (const GLOBAL_AS void*)(Bb + (size_t)srow * DIM + k0_ + scol),        \
            (LDS_AS void*)(Bs[buf] + tid * 8), 16, 0, 0);                         \
        __builtin_amdgcn_global_load_lds(                                         \
            (const GLOBAL_AS void*)(Bb + (size_t)(srow + 64) * DIM + k0_ + scol), \
            (LDS_AS void*)(Bs[buf] + 2048 + tid * 8), 16, 0, 0);                  \
    } while (0)

#define COMPUTE(buf)                                                              \
    do {                                                                          \
        bf16x8 af[4], bfr[4];                                                     \
        _Pragma("unroll")                                                         \
        for (int f = 0; f < 4; ++f)                                               \
            af[f] = *(const bf16x8*)(As[buf] + (wr * 64 + f * 16 + lr) * 32 + lk);\
        _Pragma("unroll")                                                         \
        for (int f = 0; f < 4; ++f)                                               \
            bfr[f] = *(const bf16x8*)(Bs[buf] + (wc * 64 + f * 16 + lr) * 32 + lk);\
        _Pragma("unroll")                                                         \
        for (int m = 0; m < 4; ++m)                                               \
            _Pragma("unroll")                                                     \
            for (int n = 0; n < 4; ++n)                                           \
                acc[m][n] = __builtin_amdgcn_mfma_f32_16x16x32_bf16(              \
                    af[m], bfr[n], acc[m][n], 0, 0, 0);                           \
    } while (0)

    // prologue: stage tile 0, drain, barrier
    STAGE(0, 0);
    asm volatile("s_waitcnt vmcnt(0)");
    __syncthreads();

    int cur = 0;
    for (int kt = 0; kt < DIM / 32 - 1; ++kt) {
        STAGE(cur ^ 1, kt + 1);     // next tile's loads fly during compute
        COMPUTE(cur);
        __syncthreads();            // implicit vmcnt(0)+lgkmcnt(0): next buf ready,
        cur ^= 1;                   // and all waves done reading old buf
    }
    COMPUTE(cur);                   // last tile (nothing left to stage)

    // ---- fused epilogue: d2 -> K^2 -> masked per-class accumulate ----
    float factor = (symmetric && (ti != tj)) ? 2.0f : 1.0f;
    int rowBase = ti * 128 + wr * 64;
    int colBase = tj * 128 + wc * 64;

    float cn[4], cw[4];
    int cc[4];
#pragma unroll
    for (int f = 0; f < 4; ++f) {
        int gj = colBase + f * 16 + lr;
        cn[f] = nB[gj];
        cw[f] = wB ? wB[gj] : 1.0f;
        cc[f] = cB[gj];
    }

    const float NEGF = (-2.0f / (2.0f * 32.0f * 32.0f + 1e-8f)) * 1.44269504088896340736f;
    float lacc[NC] = {0.f, 0.f, 0.f, 0.f};

#pragma unroll
    for (int m = 0; m < 4; ++m) {
#pragma unroll
        for (int j = 0; j < 4; ++j) {
            int gi = rowBase + m * 16 + (lane >> 4) * 4 + j;
            float rn = nA[gi];
            float rw = wA ? wA[gi] : 1.0f;
            int rc = cA[gi];
#pragma unroll
            for (int n = 0; n < 4; ++n) {
                float dot = acc[m][n][j];
                float d2 = rn + cn[n] - 2.0f * dot;
                d2 = fmaxf(d2, 0.0f);
                float k2 = exp2f(d2 * NEGF);        // = K^2
                float v = k2 * rw * cw[n];
#pragma unroll
                for (int c = 0; c < NC; ++c)
                    lacc[c] += ((rc == c) && (cc[n] == c)) ? v : 0.0f;
            }
        }
    }

    // block-level reduction: 4 global atomics per block instead of 16
    if (tid < NC) sred[tid] = 0.f;
    __syncthreads();
#pragma unroll
    for (int c = 0; c < NC; ++c) {
        float v = lacc[c];
        for (int off = 32; off; off >>= 1) v += __shfl_xor(v, off);
        if (lane == 0) atomicAdd(&sred[c], v);
    }
    __syncthreads();
    if (tid < NC) atomicAdd(&out[tid], factor * sred[tid]);
#undef STAGE
#undef COMPUTE
}

__global__ void finalize_kernel(const float* __restrict__ acc, float* __restrict__ out) {
    if (threadIdx.x != 0 || blockIdx.x != 0) return;
    const double EPS = 1e-8;
    const double LOG2 = 0.6931471805599453;
    double loss_cls = (double)acc[0] / NS_ROWS;
    double loss_ent = -(double)acc[1] / NT_ROWS;
    double creda_sum = 0.0, n_valid = 0.0;
    for (int c = 0; c < NC; ++c) {
        double nsc = acc[2 + c], ntc = acc[6 + c], trt = acc[10 + c];
        double sss = acc[14 + c], sst = acc[18 + c], ssst = acc[22 + c];
        double trs = nsc;
        double info_s = sss / ((trs + EPS) * (trs + EPS));
        double h_s = -log(info_s + EPS) / LOG2;
        double info_t = sst / ((trt + EPS) * (trt + EPS));
        double h_t = -log(info_t + EPS) / LOG2;
        double trm = trs + trt;
        double ssm = sss + 2.0 * ssst + sst;
        double info_m = ssm / ((trm + EPS) * (trm + EPS));
        double h_m = -log(info_m + EPS) / LOG2;
        double pc = h_m - 0.5 * (h_s + h_t);
        if (nsc >= 2.0 && ntc >= 2.0) { creda_sum += pc; n_valid += 1.0; }
    }
    double creda = (n_valid > 0.0) ? creda_sum / n_valid : 0.0;
    out[0] = (float)(loss_cls + 1.0 * creda + 0.1 * loss_ent);
}

extern "C" void kernel_launch(void* const* d_in, const int* in_sizes, int n_in,
                              void* d_out, int out_size, void* d_ws, size_t ws_size,
                              hipStream_t stream) {
    const float* FS = (const float*)d_in[0];
    const float* LS = (const float*)d_in[1];
    const float* FT = (const float*)d_in[2];
    const float* LT = (const float*)d_in[3];
    const int* LAB = (const int*)d_in[4];

    char* ws = (char*)d_ws;
    unsigned short* fs = (unsigned short*)(ws);                       // 8 MB
    unsigned short* ft = (unsigned short*)(ws + 8388608);             // 8 MB
    float* ns_ = (float*)(ws + 16777216);                             // 16 KB
    float* nt_ = ns_ + NS_ROWS;                                       // 16 KB
    float* wt2 = nt_ + NT_ROWS;                                       // 16 KB
    int* clsT = (int*)(wt2 + NT_ROWS);                                // 16 KB
    float* acc = (float*)(clsT + NT_ROWS);                            // 26 floats

    hipMemsetAsync(acc, 0, ACC_N * sizeof(float), stream);

    prep_feat<<<NS_ROWS + NT_ROWS, 128, 0, stream>>>(FS, FT, fs, ft, ns_, nt_);
    prep_rows<<<32, 256, 0, stream>>>(LS, LAB, LT, clsT, wt2, acc);

    // ss_s: symmetric source-source, 33*32/2 = 528 tiles
    gemm_reduce<<<528, 256, 0, stream>>>(fs, fs, ns_, ns_, LAB, LAB,
                                         nullptr, nullptr, acc + 14, 1);
    // ss_t: symmetric target-target with w^2 weights
    gemm_reduce<<<528, 256, 0, stream>>>(ft, ft, nt_, nt_, clsT, clsT,
                                         wt2, wt2, acc + 18, 1);
    // ss_st: source-target, full grid
    gemm_reduce<<<1024, 256, 0, stream>>>(fs, ft, ns_, nt_, LAB, clsT,
                                          nullptr, nullptr, acc + 22, 0);

    finalize_kernel<<<1, 1, 0, stream>>>(acc, (float*)d_out);
}